// Round 1
// baseline (343.496 us; speedup 1.0000x reference)
//
#include <hip/hip_runtime.h>

#define NN 64
#define PP 8732
#define CC 91
#define MM 20
#define THRESH 0.5f
#define RATIO 3

// ---------------------------------------------------------------------------
// Kernel A: per-image prior<->object matching. One block per image.
// ---------------------------------------------------------------------------
__global__ __launch_bounds__(256) void match_kernel(
    const float* __restrict__ boxes,      // N*M*4 (xyxy)
    const int*   __restrict__ labels,     // N*M
    const float* __restrict__ priors,     // P*4 (cxcywh)
    int*         __restrict__ true_classes, // N*P
    float*       __restrict__ true_locs,    // N*P*4
    int*         __restrict__ n_pos)        // N
{
  __shared__ float ov_pp[PP];       // 34.9 KB
  __shared__ short obj_pp[PP];      // 17.5 KB
  __shared__ float bx0[MM], by0[MM], bx1[MM], by1[MM], barea[MM];
  __shared__ int   lb[MM];
  __shared__ float red_v[256];
  __shared__ int   red_p[256];
  __shared__ int   prior_obj[MM];

  const int n = blockIdx.x, tid = threadIdx.x;
  if (tid < MM) {
    float4 b = ((const float4*)boxes)[n * MM + tid];
    bx0[tid] = b.x; by0[tid] = b.y; bx1[tid] = b.z; by1[tid] = b.w;
    barea[tid] = (b.z - b.x) * (b.w - b.y);
    lb[tid] = labels[n * MM + tid];
  }
  __syncthreads();

  // per-thread per-object best prior (for overlap.argmax(1))
  float bo[MM]; int bp[MM];
#pragma unroll
  for (int m = 0; m < MM; ++m) { bo[m] = -1.0f; bp[m] = 0; }

  for (int p = tid; p < PP; p += 256) {
    float4 pr = ((const float4*)priors)[p];
    float px0 = pr.x - pr.z * 0.5f, py0 = pr.y - pr.w * 0.5f;
    float px1 = pr.x + pr.z * 0.5f, py1 = pr.y + pr.w * 0.5f;
    float pa  = (px1 - px0) * (py1 - py0);
    float best = -1.0f; int bm = 0;
#pragma unroll
    for (int m = 0; m < MM; ++m) {
      float iw = fminf(bx1[m], px1) - fmaxf(bx0[m], px0);
      float ih = fminf(by1[m], py1) - fmaxf(by0[m], py0);
      iw = fmaxf(iw, 0.0f); ih = fmaxf(ih, 0.0f);
      float inter = iw * ih;
      float iou = inter / (barea[m] + pa - inter);
      if (iou > best) { best = iou; bm = m; }   // first max wins (argmax over m)
      if (iou > bo[m]) { bo[m] = iou; bp[m] = p; }  // lowest p wins on ties
    }
    ov_pp[p]  = best;
    obj_pp[p] = (short)bm;
  }
  __syncthreads();

  // block-wide argmax over priors for each object (tie -> lowest prior index)
  for (int m = 0; m < MM; ++m) {
    red_v[tid] = bo[m]; red_p[tid] = bp[m];
    __syncthreads();
    for (int s = 128; s > 0; s >>= 1) {
      if (tid < s) {
        float v2 = red_v[tid + s]; int p2 = red_p[tid + s];
        if (v2 > red_v[tid] || (v2 == red_v[tid] && p2 < red_p[tid])) {
          red_v[tid] = v2; red_p[tid] = p2;
        }
      }
      __syncthreads();
    }
    if (tid == 0) prior_obj[m] = red_p[0];
    __syncthreads();
  }

  // force each object onto its best prior; sequential so last object wins
  // (numpy scatter-set semantics for duplicate indices)
  if (tid == 0) {
    for (int m = 0; m < MM; ++m) {
      int pp = prior_obj[m];
      obj_pp[pp] = (short)m;
      ov_pp[pp]  = 1.0f;
    }
  }
  __syncthreads();

  // emit labels + encoded true locs, count positives
  int cnt = 0;
  for (int p = tid; p < PP; p += 256) {
    int   m  = obj_pp[p];
    float ov = ov_pp[p];
    int label = (ov < THRESH) ? 0 : lb[m];
    true_classes[n * PP + p] = label;
    cnt += (label != 0);
    float4 pr = ((const float4*)priors)[p];
    float cx = (bx0[m] + bx1[m]) * 0.5f, cy = (by0[m] + by1[m]) * 0.5f;
    float w  = bx1[m] - bx0[m],          h  = by1[m] - by0[m];
    float4 g;
    g.x = (cx - pr.x) / (pr.z / 10.0f);
    g.y = (cy - pr.y) / (pr.w / 10.0f);
    g.z = logf(w / pr.z) * 5.0f;
    g.w = logf(h / pr.w) * 5.0f;
    ((float4*)true_locs)[n * PP + p] = g;
  }
  red_p[tid] = cnt;
  __syncthreads();
  for (int s = 128; s > 0; s >>= 1) {
    if (tid < s) red_p[tid] += red_p[tid + s];
    __syncthreads();
  }
  if (tid == 0) n_pos[n] = red_p[0];
}

// ---------------------------------------------------------------------------
// Kernel B: per-row cross entropy (log-softmax over C=91) + fused loc loss.
// 64 rows/block, float4-coalesced LDS staging; 4 lanes per row.
// ---------------------------------------------------------------------------
__global__ __launch_bounds__(256) void ce_kernel(
    const float* __restrict__ scores,       // N*P*C
    const float* __restrict__ pred_locs,    // N*P*4
    const int*   __restrict__ true_classes, // N*P
    const float* __restrict__ true_locs,    // N*P*4
    float*       __restrict__ ce_neg,       // N*P (0 where positive)
    float*       __restrict__ acc)          // [0]=conf_pos, [1]=loc_sum
{
  const int ROWS = 64;
  __shared__ float tile[ROWS * CC];  // 23.3 KB
  __shared__ float red[256];
  const int  tid  = threadIdx.x;
  const long base = (long)blockIdx.x * ROWS;

  // coalesced float4 staging (64*91 floats divisible by 4; base offset aligned)
  const float4* src = (const float4*)scores + base * CC / 4;
  float4* dst = (float4*)tile;
  for (int t = tid; t < ROWS * CC / 4; t += 256) dst[t] = src[t];
  __syncthreads();

  const int r = tid >> 2, l = tid & 3;
  float v[23];
  float mx = -1e30f;
#pragma unroll
  for (int j = 0; j < 23; ++j) {
    int c = l + 4 * j;
    if (c < CC) { v[j] = tile[r * CC + c]; mx = fmaxf(mx, v[j]); }
  }
  mx = fmaxf(mx, __shfl_xor(mx, 1));
  mx = fmaxf(mx, __shfl_xor(mx, 2));
  float s = 0.0f;
#pragma unroll
  for (int j = 0; j < 23; ++j) {
    int c = l + 4 * j;
    if (c < CC) s += expf(v[j] - mx);
  }
  s += __shfl_xor(s, 1);
  s += __shfl_xor(s, 2);

  float cp = 0.0f, lp = 0.0f;
  if (l == 0) {
    long row = base + r;
    int label = true_classes[row];
    float xl = tile[r * CC + label];
    float ce = logf(s) + mx - xl;      // = logsumexp - x[label], always >= 0
    if (label != 0) {
      cp = ce;
      ce_neg[row] = 0.0f;
      float4 pl = ((const float4*)pred_locs)[row];
      float4 tl = ((const float4*)true_locs)[row];
      float d, a;
      d = pl.x - tl.x; a = fabsf(d); lp += (a < 1.0f) ? 0.5f * d * d : a - 0.5f;
      d = pl.y - tl.y; a = fabsf(d); lp += (a < 1.0f) ? 0.5f * d * d : a - 0.5f;
      d = pl.z - tl.z; a = fabsf(d); lp += (a < 1.0f) ? 0.5f * d * d : a - 0.5f;
      d = pl.w - tl.w; a = fabsf(d); lp += (a < 1.0f) ? 0.5f * d * d : a - 0.5f;
    } else {
      ce_neg[row] = ce;
    }
  }

  red[tid] = cp;
  __syncthreads();
  for (int st = 128; st > 0; st >>= 1) { if (tid < st) red[tid] += red[tid + st]; __syncthreads(); }
  float cpt = red[0];
  __syncthreads();
  red[tid] = lp;
  __syncthreads();
  for (int st = 128; st > 0; st >>= 1) { if (tid < st) red[tid] += red[tid + st]; __syncthreads(); }
  if (tid == 0) {
    if (cpt != 0.0f)    atomicAdd(&acc[0], cpt);
    if (red[0] != 0.0f) atomicAdd(&acc[1], red[0]);
  }
}

// ---------------------------------------------------------------------------
// Kernel C: hard-negative mining — exact top-k sum via bit-pattern bisection.
// One block per image; all ce values are non-negative so uint order == float order.
// ---------------------------------------------------------------------------
__global__ __launch_bounds__(256) void hardneg_kernel(
    const float* __restrict__ ce_neg, const int* __restrict__ n_pos,
    float* __restrict__ hard_sum)     // [N]
{
  __shared__ unsigned sv[PP];         // 34.9 KB
  __shared__ int   wred[4];
  __shared__ float wredf[4];
  const int n = blockIdx.x, tid = threadIdx.x;
  for (int p = tid; p < PP; p += 256)
    sv[p] = __float_as_uint(ce_neg[n * PP + p]);
  const int k = RATIO * n_pos[n];
  __syncthreads();

  if (k <= 0) { if (tid == 0) hard_sum[n] = 0.0f; return; }

  if (k >= PP) {  // take everything
    float s = 0.0f;
    for (int p = tid; p < PP; p += 256) s += __uint_as_float(sv[p]);
    for (int d = 1; d < 64; d <<= 1) s += __shfl_xor(s, d);
    if ((tid & 63) == 0) wredf[tid >> 6] = s;
    __syncthreads();
    if (tid == 0) hard_sum[n] = wredf[0] + wredf[1] + wredf[2] + wredf[3];
    return;
  }

  // bisection for k-th largest bit pattern:
  // invariant: count(v >= lo) >= k, count(v >= hi+1) < k
  unsigned lo = 0u, hi = 0x7f7fffffu;
  while (lo < hi) {
    unsigned mid = lo + ((hi - lo + 1u) >> 1);
    int c = 0;
    for (int p = tid; p < PP; p += 256) c += (sv[p] >= mid);
    for (int d = 1; d < 64; d <<= 1) c += __shfl_xor(c, d);
    if ((tid & 63) == 0) wred[tid >> 6] = c;
    __syncthreads();
    int total = wred[0] + wred[1] + wred[2] + wred[3];
    __syncthreads();
    if (total >= k) lo = mid; else hi = mid - 1u;
  }
  const float x = __uint_as_float(lo);   // exact k-th largest value

  float s = 0.0f; int c = 0;
  for (int p = tid; p < PP; p += 256) {
    unsigned b = sv[p];
    if (b > lo) { s += __uint_as_float(b); ++c; }
  }
  for (int d = 1; d < 64; d <<= 1) { s += __shfl_xor(s, d); c += __shfl_xor(c, d); }
  if ((tid & 63) == 0) { wredf[tid >> 6] = s; wred[tid >> 6] = c; }
  __syncthreads();
  if (tid == 0) {
    float st = wredf[0] + wredf[1] + wredf[2] + wredf[3];
    int   ct = wred[0] + wred[1] + wred[2] + wred[3];
    hard_sum[n] = st + (float)(k - ct) * x;   // exact under ties at x
  }
}

// ---------------------------------------------------------------------------
// Kernel D: final combine (single wave).
// ---------------------------------------------------------------------------
__global__ void final_kernel(const int* __restrict__ n_pos,
                             const float* __restrict__ hard_sum,
                             const float* __restrict__ acc,
                             float* __restrict__ out)
{
  const int tid = threadIdx.x;
  int   np = n_pos[tid];
  float hs = hard_sum[tid];
  for (int d = 1; d < 64; d <<= 1) { np += __shfl_xor(np, d); hs += __shfl_xor(hs, d); }
  if (tid == 0) {
    float npt = (float)np;
    out[0] = (acc[0] + hs) / npt + acc[1] / (npt * 4.0f);
  }
}

// ---------------------------------------------------------------------------
extern "C" void kernel_launch(void* const* d_in, const int* in_sizes, int n_in,
                              void* d_out, int out_size, void* d_ws, size_t ws_size,
                              hipStream_t stream) {
  const float* pred_locs   = (const float*)d_in[0];  // N*P*4
  const float* pred_scores = (const float*)d_in[1];  // N*P*C
  const float* boxes       = (const float*)d_in[2];  // N*M*4
  const int*   labels      = (const int*)d_in[3];    // N*M
  const float* priors      = (const float*)d_in[4];  // P*4
  float* out = (float*)d_out;

  float* true_locs    = (float*)d_ws;                  // N*P*4 floats
  float* ce_neg       = true_locs + (size_t)NN * PP * 4; // N*P floats
  int*   true_classes = (int*)(ce_neg + (size_t)NN * PP); // N*P ints
  int*   n_pos        = true_classes + (size_t)NN * PP;   // N ints
  float* hard_sum     = (float*)(n_pos + NN);             // N floats
  float* acc          = hard_sum + NN;                    // 2 floats

  hipMemsetAsync(acc, 0, 2 * sizeof(float), stream);

  match_kernel<<<NN, 256, 0, stream>>>(boxes, labels, priors,
                                       true_classes, true_locs, n_pos);
  ce_kernel<<<(NN * PP) / 64, 256, 0, stream>>>(pred_scores, pred_locs,
                                                true_classes, true_locs,
                                                ce_neg, acc);
  hardneg_kernel<<<NN, 256, 0, stream>>>(ce_neg, n_pos, hard_sum);
  final_kernel<<<1, 64, 0, stream>>>(n_pos, hard_sum, acc, out);
}

// Round 2
// 178.114 us; speedup vs baseline: 1.9285x; 1.9285x over previous
//
#include <hip/hip_runtime.h>

#define NN 64
#define PP 8732
#define CC 91
#define MM 20
#define THRESH 0.5f
#define RATIO 3
#define TILES ((NN * PP) / 64)   // 8732 ce tiles of 64 rows

// ---------------------------------------------------------------------------
// Kernel A: per-image prior<->object matching. One block (256 thr) per image.
// ---------------------------------------------------------------------------
__global__ __launch_bounds__(256) void match_kernel(
    const float* __restrict__ boxes,      // N*M*4 (xyxy)
    const int*   __restrict__ labels,     // N*M
    const float* __restrict__ priors,     // P*4 (cxcywh)
    int*         __restrict__ true_classes, // N*P
    float*       __restrict__ true_locs,    // N*P*4
    int*         __restrict__ n_pos)        // N
{
  __shared__ float ov_pp[PP];       // 34.9 KB
  __shared__ short obj_pp[PP];      // 17.5 KB
  __shared__ float bx0[MM], by0[MM], bx1[MM], by1[MM], barea[MM];
  __shared__ int   lb[MM];
  __shared__ float wv[4][MM];
  __shared__ int   wp[4][MM];
  __shared__ int   wcnt[4];

  const int n = blockIdx.x, tid = threadIdx.x;
  const int wave = tid >> 6, lane = tid & 63;
  if (tid < MM) {
    float4 b = ((const float4*)boxes)[n * MM + tid];
    bx0[tid] = b.x; by0[tid] = b.y; bx1[tid] = b.z; by1[tid] = b.w;
    barea[tid] = (b.z - b.x) * (b.w - b.y);
    lb[tid] = labels[n * MM + tid];
  }
  __syncthreads();

  // per-thread per-object best prior (for overlap.argmax(1))
  float bo[MM]; int bp[MM];
#pragma unroll
  for (int m = 0; m < MM; ++m) { bo[m] = -1.0f; bp[m] = 0x7fffffff; }

  for (int p = tid; p < PP; p += 256) {
    float4 pr = ((const float4*)priors)[p];
    float px0 = pr.x - pr.z * 0.5f, py0 = pr.y - pr.w * 0.5f;
    float px1 = pr.x + pr.z * 0.5f, py1 = pr.y + pr.w * 0.5f;
    float pa  = (px1 - px0) * (py1 - py0);
    float best = -1.0f; int bm = 0;
#pragma unroll
    for (int m = 0; m < MM; ++m) {
      float iw = fminf(bx1[m], px1) - fmaxf(bx0[m], px0);
      float ih = fminf(by1[m], py1) - fmaxf(by0[m], py0);
      iw = fmaxf(iw, 0.0f); ih = fmaxf(ih, 0.0f);
      float inter = iw * ih;
      float iou = inter / (barea[m] + pa - inter);
      if (iou > best) { best = iou; bm = m; }       // first max wins (over m)
      if (iou > bo[m]) { bo[m] = iou; bp[m] = p; }  // lowest p wins on ties
    }
    ov_pp[p]  = best;
    obj_pp[p] = (short)bm;
  }

  // wave-level argmax per object: lexicographic max of (v, -p) -> associative
#pragma unroll
  for (int m = 0; m < MM; ++m) {
#pragma unroll
    for (int d = 1; d < 64; d <<= 1) {
      float v2 = __shfl_xor(bo[m], d);
      int   p2 = __shfl_xor(bp[m], d);
      if (v2 > bo[m] || (v2 == bo[m] && p2 < bp[m])) { bo[m] = v2; bp[m] = p2; }
    }
    if (lane == 0) { wv[wave][m] = bo[m]; wp[wave][m] = bp[m]; }
  }
  __syncthreads();   // ov_pp/obj_pp complete + wv/wp visible

  // tid 0: combine 4 waves per object, then sequential override (last wins)
  if (tid == 0) {
#pragma unroll
    for (int m = 0; m < MM; ++m) {
      float v = wv[0][m]; int p = wp[0][m];
      for (int w = 1; w < 4; ++w) {
        float v2 = wv[w][m]; int p2 = wp[w][m];
        if (v2 > v || (v2 == v && p2 < p)) { v = v2; p = p2; }
      }
      obj_pp[p] = (short)m;
      ov_pp[p]  = 1.0f;
    }
  }
  __syncthreads();

  // emit labels + encoded true locs, count positives
  int cnt = 0;
  for (int p = tid; p < PP; p += 256) {
    int   m  = obj_pp[p];
    float ov = ov_pp[p];
    int label = (ov < THRESH) ? 0 : lb[m];
    true_classes[n * PP + p] = label;
    cnt += (label != 0);
    float4 pr = ((const float4*)priors)[p];
    float cx = (bx0[m] + bx1[m]) * 0.5f, cy = (by0[m] + by1[m]) * 0.5f;
    float w  = bx1[m] - bx0[m],          h  = by1[m] - by0[m];
    float4 g;
    g.x = (cx - pr.x) / (pr.z / 10.0f);
    g.y = (cy - pr.y) / (pr.w / 10.0f);
    g.z = logf(w / pr.z) * 5.0f;
    g.w = logf(h / pr.w) * 5.0f;
    ((float4*)true_locs)[n * PP + p] = g;
  }
#pragma unroll
  for (int d = 1; d < 64; d <<= 1) cnt += __shfl_xor(cnt, d);
  if (lane == 0) wcnt[wave] = cnt;
  __syncthreads();
  if (tid == 0) n_pos[n] = wcnt[0] + wcnt[1] + wcnt[2] + wcnt[3];
}

// ---------------------------------------------------------------------------
// Kernel B: per-row CE (log-softmax over C=91) + fused smooth-L1 loc loss.
// 64 rows/block, float4 LDS staging, 4 lanes/row, two LDS passes
// (NO per-thread array -> no scratch spill), NO atomics (per-block partials).
// ---------------------------------------------------------------------------
__global__ __launch_bounds__(256) void ce_kernel(
    const float* __restrict__ scores,       // N*P*C
    const float* __restrict__ pred_locs,    // N*P*4
    const int*   __restrict__ true_classes, // N*P
    const float* __restrict__ true_locs,    // N*P*4
    float*       __restrict__ ce_neg,       // N*P (0 where positive)
    float2*      __restrict__ partials)     // [TILES] (conf_pos, loc_sum)
{
  __shared__ float tile[64 * CC];  // 23.3 KB
  __shared__ float2 wpart[4];
  const int  tid  = threadIdx.x;
  const long base = (long)blockIdx.x * 64;
  const int  r = tid >> 2, l = tid & 3;

  // prefetch (hides latency under staging)
  const int label = true_classes[base + r];
  float4 pl, tl;
  if (l == 0) {
    pl = ((const float4*)pred_locs)[base + r];
    tl = ((const float4*)true_locs)[base + r];
  }

  // coalesced float4 staging: 64*91 = 5824 floats = 1456 float4
  {
    const float4* src = (const float4*)scores + base * CC / 4;
    float4* dst = (float4*)tile;
#pragma unroll
    for (int t = 0; t < 6; ++t) {
      int idx = tid + t * 256;
      if (idx < (64 * CC) / 4) dst[idx] = src[idx];
    }
  }
  __syncthreads();

  const float* row = &tile[r * CC];
  float mx = -1e30f;
  for (int c = l; c < CC; c += 4) mx = fmaxf(mx, row[c]);
  mx = fmaxf(mx, __shfl_xor(mx, 1));
  mx = fmaxf(mx, __shfl_xor(mx, 2));
  float s = 0.0f;
  for (int c = l; c < CC; c += 4) s += expf(row[c] - mx);
  s += __shfl_xor(s, 1);
  s += __shfl_xor(s, 2);

  float cp = 0.0f, lp = 0.0f;
  if (l == 0) {
    float ce = logf(s) + mx - row[label];   // logsumexp - x[label] >= 0
    if (label != 0) {
      cp = ce;
      ce_neg[base + r] = 0.0f;
      float d, a;
      d = pl.x - tl.x; a = fabsf(d); lp += (a < 1.0f) ? 0.5f * d * d : a - 0.5f;
      d = pl.y - tl.y; a = fabsf(d); lp += (a < 1.0f) ? 0.5f * d * d : a - 0.5f;
      d = pl.z - tl.z; a = fabsf(d); lp += (a < 1.0f) ? 0.5f * d * d : a - 0.5f;
      d = pl.w - tl.w; a = fabsf(d); lp += (a < 1.0f) ? 0.5f * d * d : a - 0.5f;
    } else {
      ce_neg[base + r] = ce;
    }
  }

  // wave butterfly + 4-entry LDS combine (one barrier, no atomics)
#pragma unroll
  for (int d = 1; d < 64; d <<= 1) {
    cp += __shfl_xor(cp, d);
    lp += __shfl_xor(lp, d);
  }
  if ((tid & 63) == 0) wpart[tid >> 6] = make_float2(cp, lp);
  __syncthreads();
  if (tid == 0) {
    float2 a0 = wpart[0], a1 = wpart[1], a2 = wpart[2], a3 = wpart[3];
    partials[blockIdx.x] = make_float2(a0.x + a1.x + a2.x + a3.x,
                                       a0.y + a1.y + a2.y + a3.y);
  }
}

// ---------------------------------------------------------------------------
// Kernel C: hard-negative mining — exact top-k sum via bit-pattern bisection.
// One block per image; all ce values >= 0 so uint order == float order.
// ---------------------------------------------------------------------------
__global__ __launch_bounds__(256) void hardneg_kernel(
    const float* __restrict__ ce_neg, const int* __restrict__ n_pos,
    float* __restrict__ hard_sum)     // [N]
{
  __shared__ unsigned sv[PP];         // 34.9 KB
  __shared__ int   wred[4];
  __shared__ float wredf[4];
  const int n = blockIdx.x, tid = threadIdx.x;
  for (int p = tid; p < PP; p += 256)
    sv[p] = __float_as_uint(ce_neg[n * PP + p]);
  const int k = RATIO * n_pos[n];
  __syncthreads();

  if (k <= 0) { if (tid == 0) hard_sum[n] = 0.0f; return; }

  if (k >= PP) {  // take everything
    float s = 0.0f;
    for (int p = tid; p < PP; p += 256) s += __uint_as_float(sv[p]);
#pragma unroll
    for (int d = 1; d < 64; d <<= 1) s += __shfl_xor(s, d);
    if ((tid & 63) == 0) wredf[tid >> 6] = s;
    __syncthreads();
    if (tid == 0) hard_sum[n] = wredf[0] + wredf[1] + wredf[2] + wredf[3];
    return;
  }

  // bisection for k-th largest bit pattern:
  // invariant: count(v >= lo) >= k, count(v >= hi+1) < k
  unsigned lo = 0u, hi = 0x7f7fffffu;
  while (lo < hi) {
    unsigned mid = lo + ((hi - lo + 1u) >> 1);
    int c = 0;
    for (int p = tid; p < PP; p += 256) c += (sv[p] >= mid);
#pragma unroll
    for (int d = 1; d < 64; d <<= 1) c += __shfl_xor(c, d);
    if ((tid & 63) == 0) wred[tid >> 6] = c;
    __syncthreads();
    int total = wred[0] + wred[1] + wred[2] + wred[3];
    __syncthreads();
    if (total >= k) lo = mid; else hi = mid - 1u;
  }
  const float x = __uint_as_float(lo);   // exact k-th largest value

  float s = 0.0f; int c = 0;
  for (int p = tid; p < PP; p += 256) {
    unsigned b = sv[p];
    if (b > lo) { s += __uint_as_float(b); ++c; }
  }
#pragma unroll
  for (int d = 1; d < 64; d <<= 1) { s += __shfl_xor(s, d); c += __shfl_xor(c, d); }
  if ((tid & 63) == 0) { wredf[tid >> 6] = s; wred[tid >> 6] = c; }
  __syncthreads();
  if (tid == 0) {
    float st = wredf[0] + wredf[1] + wredf[2] + wredf[3];
    int   ct = wred[0] + wred[1] + wred[2] + wred[3];
    hard_sum[n] = st + (float)(k - ct) * x;   // exact under ties at x
  }
}

// ---------------------------------------------------------------------------
// Kernel D: final combine — reduce ce partials + n_pos + hard_sum.
// ---------------------------------------------------------------------------
__global__ __launch_bounds__(256) void final_kernel(
    const int* __restrict__ n_pos, const float* __restrict__ hard_sum,
    const float2* __restrict__ partials, float* __restrict__ out)
{
  __shared__ float2 wred2[4];
  const int tid = threadIdx.x;
  float cp = 0.0f, lp = 0.0f;
  for (int i = tid; i < TILES; i += 256) {
    float2 v = partials[i];
    cp += v.x; lp += v.y;
  }
  float np = 0.0f, hs = 0.0f;
  if (tid < NN) { np = (float)n_pos[tid]; hs = hard_sum[tid]; }
#pragma unroll
  for (int d = 1; d < 64; d <<= 1) {
    cp += __shfl_xor(cp, d); lp += __shfl_xor(lp, d);
    np += __shfl_xor(np, d); hs += __shfl_xor(hs, d);
  }
  if ((tid & 63) == 0) wred2[tid >> 6] = make_float2(cp, lp);
  __syncthreads();
  if (tid == 0) {
    float cpt = wred2[0].x + wred2[1].x + wred2[2].x + wred2[3].x;
    float lpt = wred2[0].y + wred2[1].y + wred2[2].y + wred2[3].y;
    out[0] = (cpt + hs) / np + lpt / (np * 4.0f);   // np, hs reduced in wave 0
  }
}

// ---------------------------------------------------------------------------
extern "C" void kernel_launch(void* const* d_in, const int* in_sizes, int n_in,
                              void* d_out, int out_size, void* d_ws, size_t ws_size,
                              hipStream_t stream) {
  const float* pred_locs   = (const float*)d_in[0];  // N*P*4
  const float* pred_scores = (const float*)d_in[1];  // N*P*C
  const float* boxes       = (const float*)d_in[2];  // N*M*4
  const int*   labels      = (const int*)d_in[3];    // N*M
  const float* priors      = (const float*)d_in[4];  // P*4
  float* out = (float*)d_out;

  float* true_locs    = (float*)d_ws;                     // N*P*4 floats
  float* ce_neg       = true_locs + (size_t)NN * PP * 4;  // N*P floats
  int*   true_classes = (int*)(ce_neg + (size_t)NN * PP); // N*P ints
  int*   n_pos        = true_classes + (size_t)NN * PP;   // N ints
  float* hard_sum     = (float*)(n_pos + NN);             // N floats
  float2* partials    = (float2*)(hard_sum + NN);         // TILES float2 (8B-aligned)

  match_kernel<<<NN, 256, 0, stream>>>(boxes, labels, priors,
                                       true_classes, true_locs, n_pos);
  ce_kernel<<<TILES, 256, 0, stream>>>(pred_scores, pred_locs,
                                       true_classes, true_locs,
                                       ce_neg, partials);
  hardneg_kernel<<<NN, 256, 0, stream>>>(ce_neg, n_pos, hard_sum);
  final_kernel<<<1, 256, 0, stream>>>(n_pos, hard_sum, partials, out);
}

// Round 3
// 143.144 us; speedup vs baseline: 2.3997x; 1.2443x over previous
//
#include <hip/hip_runtime.h>

#define NN 64
#define PP 8732
#define CC 91
#define MM 20
#define RATIO 3
#define TILES ((NN * PP) / 64)   // 8732 ce tiles of 64 rows
#define BPI 8                    // match blocks per image
#define CHUNK 1092               // ceil(PP / BPI)

// ---------------------------------------------------------------------------
// Kernel A: matching, phase A. 8 blocks/image (512 total). Division-free
// IoU compares via cross-multiplication; per-object global argmax via
// packed-key atomicMax(u64): key = float_bits(iou)<<32 | ~prior_idx.
// ---------------------------------------------------------------------------
__global__ __launch_bounds__(256) void match_a(
    const float4* __restrict__ boxes4,   // N*M (xyxy)
    const float4* __restrict__ priors4,  // P (cxcywh)
    float2* __restrict__ numden,         // N*P (inter, den) of best object
    unsigned char* __restrict__ obj8,    // N*P argmax object
    unsigned long long* __restrict__ combined) // N*M packed best (pre-zeroed)
{
  __shared__ float bx0[MM], by0[MM], bx1[MM], by1[MM], ba[MM];
  const int blk = blockIdx.x, tid = threadIdx.x, lane = tid & 63;
  const int n = blk >> 3, part = blk & 7;
  const int c0 = part * CHUNK;
  const int cend = (c0 + CHUNK < PP) ? c0 + CHUNK : PP;

  if (tid < MM) {
    float4 b = boxes4[n * MM + tid];
    bx0[tid] = b.x; by0[tid] = b.y; bx1[tid] = b.z; by1[tid] = b.w;
    ba[tid] = (b.z - b.x) * (b.w - b.y);
  }
  __syncthreads();

  float bi[MM], bd[MM]; int bpp[MM];
#pragma unroll
  for (int m = 0; m < MM; ++m) { bi[m] = -1.0f; bd[m] = 1.0f; bpp[m] = 0; }

#pragma unroll
  for (int i = 0; i < 5; ++i) {
    int p = c0 + tid + i * 256;
    if (p < cend) {
      float4 pr = priors4[p];
      float hw = pr.z * 0.5f, hh = pr.w * 0.5f;
      float px0 = pr.x - hw, py0 = pr.y - hh, px1 = pr.x + hw, py1 = pr.y + hh;
      float pa = (px1 - px0) * (py1 - py0);   // match ref rounding exactly
      float pi = -1.0f, pd = 1.0f; int pm = 0;
#pragma unroll
      for (int m = 0; m < MM; ++m) {
        float iw = fminf(bx1[m], px1) - fmaxf(bx0[m], px0);
        float ih = fminf(by1[m], py1) - fmaxf(by0[m], py0);
        iw = fmaxf(iw, 0.0f); ih = fmaxf(ih, 0.0f);
        float inter = iw * ih;
        float den = (ba[m] + pa) - inter;
        // per-prior argmax over m (strict > => first m wins ties)
        bool c1 = inter * pd > pi * den;
        pi = c1 ? inter : pi; pd = c1 ? den : pd; pm = c1 ? m : pm;
        // per-object argmax over p (strict > => lowest p wins ties)
        bool c2 = inter * bd[m] > bi[m] * den;
        bi[m] = c2 ? inter : bi[m]; bd[m] = c2 ? den : bd[m];
        bpp[m] = c2 ? p : bpp[m];
      }
      numden[(size_t)n * PP + p] = make_float2(pi, pd);
      obj8[(size_t)n * PP + p] = (unsigned char)pm;
    }
  }

  // per-object: one division (matches ref rounding), pack, wave-reduce, atomic
#pragma unroll
  for (int m = 0; m < MM; ++m) {
    float r = bi[m] / bd[m];                   // iou >= 0 -> bits monotone
    unsigned long long key =
        ((unsigned long long)__float_as_uint(r) << 32) |
        (unsigned)(~(unsigned)bpp[m]);         // lower p -> larger key
#pragma unroll
    for (int d = 1; d < 64; d <<= 1) {
      unsigned long long o = __shfl_xor(key, d);
      key = (o > key) ? o : key;
    }
    if (lane == 0) atomicMax(&combined[n * MM + m], key);
  }
}

// ---------------------------------------------------------------------------
// Kernel B: CE + matching emit + loc loss, fused. 64 rows/block.
// ---------------------------------------------------------------------------
__global__ __launch_bounds__(256) void ce_kernel(
    const float* __restrict__ scores,        // N*P*C
    const float4* __restrict__ pred_locs4,   // N*P
    const float4* __restrict__ priors4,      // P
    const float4* __restrict__ boxes4,       // N*M
    const int* __restrict__ labels,          // N*M
    const float2* __restrict__ numden,       // N*P
    const unsigned char* __restrict__ obj8,  // N*P
    const unsigned long long* __restrict__ combined, // N*M
    float* __restrict__ ce_neg,              // N*P (0 where positive)
    float2* __restrict__ partials,           // [TILES] (conf_pos, loc_sum)
    int* __restrict__ n_pos)                 // [N] (pre-zeroed, atomicAdd)
{
  __shared__ float tile[64 * CC];            // 23.3 KB
  __shared__ unsigned key_lo[2][MM];
  __shared__ int lbl_s[2][MM];
  __shared__ float4 box_s[2][MM];
  __shared__ float2 wpart[4];
  __shared__ int wc0[4], wc1[4];
  const int tid = threadIdx.x;
  const int base = blockIdx.x * 64;
  const int n0 = base / PP;
  const int rem0 = base - n0 * PP;

  // stage scores (coalesced float4; 1456 vec4 per tile)
  {
    const float4* src = (const float4*)scores + (size_t)base * CC / 4;
    float4* dst = (float4*)tile;
#pragma unroll
    for (int i = 0; i < 6; ++i) {
      int idx = tid + i * 256;
      if (idx < (64 * CC) / 4) dst[idx] = src[idx];
    }
  }
  // stage per-image tables (block spans at most 2 images)
  if (tid < MM) {
    key_lo[0][tid] = (unsigned)(combined[n0 * MM + tid] & 0xffffffffull);
    lbl_s[0][tid]  = labels[n0 * MM + tid];
    box_s[0][tid]  = boxes4[n0 * MM + tid];
  } else if (tid >= 64 && tid < 64 + MM) {
    int j = tid - 64, nn = (n0 + 1 < NN) ? n0 + 1 : NN - 1;
    key_lo[1][j] = (unsigned)(combined[nn * MM + j] & 0xffffffffull);
    lbl_s[1][j]  = labels[nn * MM + j];
    box_s[1][j]  = boxes4[nn * MM + j];
  }
  __syncthreads();

  const int r = tid >> 2, l = tid & 3;
  const float* rowp = &tile[r * CC];
  float mx = -1e30f;
  for (int c = l; c < CC; c += 4) mx = fmaxf(mx, rowp[c]);
  mx = fmaxf(mx, __shfl_xor(mx, 1));
  mx = fmaxf(mx, __shfl_xor(mx, 2));
  float s = 0.0f;
  for (int c = l; c < CC; c += 4) s += __expf(rowp[c] - mx);
  s += __shfl_xor(s, 1);
  s += __shfl_xor(s, 2);

  float cp = 0.0f, lp = 0.0f; int pos0 = 0, pos1 = 0;
  if (l == 0) {
    const int row = base + r;
    const int bn = (rem0 + r >= PP) ? 1 : 0;
    const int p = rem0 + r - bn * PP;
    float2 nd = numden[row];
    int o = obj8[row];
    // override scan: was this prior some object's best? (ascending, last wins)
    int mm = -1;
    const unsigned want = ~(unsigned)p;
#pragma unroll
    for (int j = 0; j < MM; ++j) if (key_lo[bn][j] == want) mm = j;
    bool pos; int lab, sm;
    if (mm >= 0) { pos = true; sm = mm; lab = lbl_s[bn][mm]; }
    else {
      pos = !(nd.x < 0.5f * nd.y);      // iou < 0.5 -> background
      sm = o; lab = pos ? lbl_s[bn][o] : 0;
    }
    float ce = __logf(s) + mx - rowp[lab];
    if (pos) {
      cp = ce; ce_neg[row] = 0.0f;
      if (bn) pos1 = 1; else pos0 = 1;
      float4 bx = box_s[bn][sm], pr = priors4[p], pl = pred_locs4[row];
      float cx = (bx.x + bx.z) * 0.5f, cy = (bx.y + bx.w) * 0.5f;
      float w = bx.z - bx.x, h = bx.w - bx.y;
      float gx = (cx - pr.x) / (pr.z / 10.0f);
      float gy = (cy - pr.y) / (pr.w / 10.0f);
      float gz = __logf(w / pr.z) * 5.0f;
      float gw = __logf(h / pr.w) * 5.0f;
      float d, a;
      d = pl.x - gx; a = fabsf(d); lp += (a < 1.0f) ? 0.5f * d * d : a - 0.5f;
      d = pl.y - gy; a = fabsf(d); lp += (a < 1.0f) ? 0.5f * d * d : a - 0.5f;
      d = pl.z - gz; a = fabsf(d); lp += (a < 1.0f) ? 0.5f * d * d : a - 0.5f;
      d = pl.w - gw; a = fabsf(d); lp += (a < 1.0f) ? 0.5f * d * d : a - 0.5f;
    } else {
      ce_neg[row] = ce;
    }
  }

#pragma unroll
  for (int d = 1; d < 64; d <<= 1) {
    cp += __shfl_xor(cp, d); lp += __shfl_xor(lp, d);
    pos0 += __shfl_xor(pos0, d); pos1 += __shfl_xor(pos1, d);
  }
  if ((tid & 63) == 0) {
    wpart[tid >> 6] = make_float2(cp, lp);
    wc0[tid >> 6] = pos0; wc1[tid >> 6] = pos1;
  }
  __syncthreads();
  if (tid == 0) {
    float sx = 0.f, sy = 0.f; int c0 = 0, c1 = 0;
    for (int w = 0; w < 4; ++w) {
      sx += wpart[w].x; sy += wpart[w].y; c0 += wc0[w]; c1 += wc1[w];
    }
    partials[blockIdx.x] = make_float2(sx, sy);
    if (c0) atomicAdd(&n_pos[n0], c0);
    if (c1) atomicAdd(&n_pos[(n0 + 1 < NN) ? n0 + 1 : NN - 1], c1);
  }
}

// ---------------------------------------------------------------------------
// Kernel C: hard-negative mining — register-resident bisection for exact
// top-k sum (all ce >= 0 so uint order == float order). One block/image.
// ---------------------------------------------------------------------------
__global__ __launch_bounds__(256) void hardneg_kernel(
    const float* __restrict__ ce_neg, const int* __restrict__ n_pos,
    float* __restrict__ hard_sum)
{
  __shared__ int wred[2][4];
  __shared__ float wredf[4];
  __shared__ int wcnt[4];
  const int n = blockIdx.x, tid = threadIdx.x;
  unsigned uv[35];
#pragma unroll
  for (int i = 0; i < 35; ++i) {
    int p = tid + i * 256;
    uv[i] = (p < PP) ? __float_as_uint(ce_neg[(size_t)n * PP + p]) : 0u;
  }
  const int k = RATIO * n_pos[n];
  if (k <= 0) { if (tid == 0) hard_sum[n] = 0.0f; return; }

  if (k >= PP) {   // take all negatives
    float s = 0.0f;
#pragma unroll
    for (int i = 0; i < 35; ++i) s += __uint_as_float(uv[i]);
#pragma unroll
    for (int d = 1; d < 64; d <<= 1) s += __shfl_xor(s, d);
    if ((tid & 63) == 0) wredf[tid >> 6] = s;
    __syncthreads();
    if (tid == 0) hard_sum[n] = wredf[0] + wredf[1] + wredf[2] + wredf[3];
    return;
  }

  // bisect for k-th largest bit pattern; counts from registers
  unsigned lo = 0u, hi = 0x7f7fffffu;
  int it = 0;
  while (lo < hi) {
    unsigned mid = lo + ((hi - lo + 1u) >> 1);
    int c = 0;
#pragma unroll
    for (int i = 0; i < 35; ++i) c += (uv[i] >= mid);
#pragma unroll
    for (int d = 1; d < 64; d <<= 1) c += __shfl_xor(c, d);
    const int buf = it & 1;
    if ((tid & 63) == 0) wred[buf][tid >> 6] = c;
    __syncthreads();
    int total = wred[buf][0] + wred[buf][1] + wred[buf][2] + wred[buf][3];
    if (total >= k) lo = mid; else hi = mid - 1u;
    ++it;
  }
  const float x = __uint_as_float(lo);   // exact k-th largest

  float s = 0.0f; int c = 0;
#pragma unroll
  for (int i = 0; i < 35; ++i) {
    unsigned b = uv[i];
    if (b > lo) { s += __uint_as_float(b); ++c; }
  }
#pragma unroll
  for (int d = 1; d < 64; d <<= 1) { s += __shfl_xor(s, d); c += __shfl_xor(c, d); }
  if ((tid & 63) == 0) { wredf[tid >> 6] = s; wcnt[tid >> 6] = c; }
  __syncthreads();
  if (tid == 0) {
    float st = wredf[0] + wredf[1] + wredf[2] + wredf[3];
    int   ct = wcnt[0] + wcnt[1] + wcnt[2] + wcnt[3];
    hard_sum[n] = st + (float)(k - ct) * x;   // exact under ties at x
  }
}

// ---------------------------------------------------------------------------
// Kernel D: final combine.
// ---------------------------------------------------------------------------
__global__ __launch_bounds__(256) void final_kernel(
    const int* __restrict__ n_pos, const float* __restrict__ hard_sum,
    const float2* __restrict__ partials, float* __restrict__ out)
{
  __shared__ float2 w2[4];
  const int tid = threadIdx.x;
  float cp = 0.0f, lp = 0.0f;
  for (int i = tid; i < TILES; i += 256) {
    float2 v = partials[i];
    cp += v.x; lp += v.y;
  }
  float np = 0.0f, hs = 0.0f;
  if (tid < NN) { np = (float)n_pos[tid]; hs = hard_sum[tid]; }
#pragma unroll
  for (int d = 1; d < 64; d <<= 1) {
    cp += __shfl_xor(cp, d); lp += __shfl_xor(lp, d);
    np += __shfl_xor(np, d); hs += __shfl_xor(hs, d);
  }
  if ((tid & 63) == 0) w2[tid >> 6] = make_float2(cp, lp);
  __syncthreads();
  if (tid == 0) {
    float cpt = w2[0].x + w2[1].x + w2[2].x + w2[3].x;
    float lpt = w2[0].y + w2[1].y + w2[2].y + w2[3].y;
    out[0] = (cpt + hs) / np + lpt / (np * 4.0f);  // np,hs full-sums in wave 0
  }
}

// ---------------------------------------------------------------------------
extern "C" void kernel_launch(void* const* d_in, const int* in_sizes, int n_in,
                              void* d_out, int out_size, void* d_ws, size_t ws_size,
                              hipStream_t stream) {
  const float*  pred_locs   = (const float*)d_in[0];
  const float*  pred_scores = (const float*)d_in[1];
  const float*  boxes       = (const float*)d_in[2];
  const int*    labels      = (const int*)d_in[3];
  const float*  priors      = (const float*)d_in[4];
  float* out = (float*)d_out;

  // workspace layout (16B-aligned base)
  float2* numden = (float2*)d_ws;                                // N*P
  float2* partials = numden + (size_t)NN * PP;                   // TILES
  float*  ce_neg = (float*)(partials + TILES);                   // N*P
  unsigned long long* combined =
      (unsigned long long*)(ce_neg + (size_t)NN * PP);           // N*M
  int*    n_pos = (int*)(combined + NN * MM);                    // N
  float*  hard_sum = (float*)(n_pos + NN);                       // N
  unsigned char* obj8 = (unsigned char*)(hard_sum + NN);         // N*P

  // zero combined + n_pos in one memset (contiguous)
  hipMemsetAsync(combined, 0, NN * MM * 8 + NN * 4, stream);

  match_a<<<NN * BPI, 256, 0, stream>>>((const float4*)boxes,
                                        (const float4*)priors,
                                        numden, obj8, combined);
  ce_kernel<<<TILES, 256, 0, stream>>>(pred_scores, (const float4*)pred_locs,
                                       (const float4*)priors,
                                       (const float4*)boxes, labels,
                                       numden, obj8, combined,
                                       ce_neg, partials, n_pos);
  hardneg_kernel<<<NN, 256, 0, stream>>>(ce_neg, n_pos, hard_sum);
  final_kernel<<<1, 256, 0, stream>>>(n_pos, hard_sum, partials, out);
}